// Round 1
// baseline (845.678 us; speedup 1.0000x reference)
//
#include <hip/hip_runtime.h>
#include <hip/hip_bf16.h>

// SCNN: 3 spectral-conv branches (2 layers each) -> sum over S -> 3-layer MLP.
// Round 1: correctness-first f32 baseline.
//   - F-dimension collapsed: sum_f relu(Lx*Wc[f]) == relu(Lx)*P + relu(-Lx)*M
//   - conv GEMM: C[m,j] = sum_k A[m,k]*L[j,k]  (A=x rows are b*S+s), fused epilogue
//   - MLP: split-K partial GEMMs + deterministic reduce (no float atomics)

#define B_    32
#define S_    8
#define BS_   256      // B_*S_
#define F_    4
#define IN_   8192
#define H_    1024
#define OUT_  256

// ---------------- prep: P/M from Wc ----------------
__global__ void k_prep(const float* __restrict__ Wc0, const float* __restrict__ Wc1,
                       const float* __restrict__ Wc2, float* __restrict__ PM) {
    int idx = blockIdx.x * 256 + threadIdx.x;      // [0, 2*IN_)
    if (idx >= 2 * IN_) return;
    int l = idx / IN_, n = idx % IN_;
    const float* Wc; int nb, j;
    if (n < 2048)      { Wc = Wc0; nb = 2048; j = n;        }
    else if (n < 6144) { Wc = Wc1; nb = 4096; j = n - 2048; }
    else               { Wc = Wc2; nb = 2048; j = n - 6144; }
    float p = 0.f, m = 0.f;
    #pragma unroll
    for (int f = 0; f < F_; ++f) {
        float w = Wc[(l * F_ + f) * nb + j];
        p += fmaxf(w, 0.f);
        m += fmaxf(-w, 0.f);
    }
    PM[(l * 2 + 0) * IN_ + n] = p;
    PM[(l * 2 + 1) * IN_ + n] = m;
}

// ---------------- conv GEMM (all 3 branches in one grid) ----------------
// BM=128, BN=64, BK=32, 256 threads, 8x4 per thread.
// grid: b0 tiles [0,64), b1 [64,192), b2 [192,256)
__global__ __launch_bounds__(256) void k_conv(
    const float* __restrict__ A0, const float* __restrict__ A1, const float* __restrict__ A2,
    int lda0, int lda1, int lda2,
    const float* __restrict__ L0, const float* __restrict__ L1, const float* __restrict__ L2,
    const float* __restrict__ Pv, const float* __restrict__ Mv,
    float* __restrict__ Dst)   // concat layout [BS_][IN_]
{
    __shared__ float As[32][128 + 4];   // k-major, +4 keeps rows 16B-aligned
    __shared__ float Bs[32][64 + 4];

    int bx = blockIdx.x;
    const float *A, *L; int lda, n_, noff, mt, nt;
    if (bx < 64)       { int t = bx;       mt = t >> 5; nt = t & 31; n_ = 2048; noff = 0;    A = A0; L = L0; lda = lda0; }
    else if (bx < 192) { int t = bx - 64;  mt = t >> 6; nt = t & 63; n_ = 4096; noff = 2048; A = A1; L = L1; lda = lda1; }
    else               { int t = bx - 192; mt = t >> 5; nt = t & 31; n_ = 2048; noff = 6144; A = A2; L = L2; lda = lda2; }

    const int tid = threadIdx.x;
    const int m0 = mt * 128, jg0 = nt * 64;
    const int tr = tid & 15, tc = tid >> 4;

    float acc[8][4];
    #pragma unroll
    for (int i = 0; i < 8; ++i)
        #pragma unroll
        for (int j = 0; j < 4; ++j) acc[i][j] = 0.f;

    for (int kt = 0; kt < n_; kt += 32) {
        // stage A tile: 128 rows x 32 k  (transposed write -> k-major)
        #pragma unroll
        for (int v = 0; v < 4; ++v) {
            int vid = (v << 8) + tid;           // 0..1023
            int row = vid >> 3, seg = (vid & 7) << 2;
            float4 a4 = *(const float4*)(A + (size_t)(m0 + row) * lda + kt + seg);
            As[seg + 0][row] = a4.x; As[seg + 1][row] = a4.y;
            As[seg + 2][row] = a4.z; As[seg + 3][row] = a4.w;
        }
        // stage B tile: 64 rows(j) x 32 k
        #pragma unroll
        for (int v = 0; v < 2; ++v) {
            int vid = (v << 8) + tid;           // 0..511
            int row = vid >> 3, seg = (vid & 7) << 2;
            float4 b4 = *(const float4*)(L + (size_t)(jg0 + row) * n_ + kt + seg);
            Bs[seg + 0][row] = b4.x; Bs[seg + 1][row] = b4.y;
            Bs[seg + 2][row] = b4.z; Bs[seg + 3][row] = b4.w;
        }
        __syncthreads();
        #pragma unroll
        for (int kk = 0; kk < 32; ++kk) {
            float4 a0 = *(const float4*)&As[kk][tr * 8];
            float4 a1 = *(const float4*)&As[kk][tr * 8 + 4];
            float4 b  = *(const float4*)&Bs[kk][tc * 4];
            float av[8] = {a0.x, a0.y, a0.z, a0.w, a1.x, a1.y, a1.z, a1.w};
            float bv[4] = {b.x, b.y, b.z, b.w};
            #pragma unroll
            for (int i = 0; i < 8; ++i)
                #pragma unroll
                for (int j = 0; j < 4; ++j)
                    acc[i][j] = fmaf(av[i], bv[j], acc[i][j]);
        }
        __syncthreads();
    }

    // fused epilogue: x_next = relu(Lx)*P + relu(-Lx)*M, write concat layout
    const int ncol = noff + jg0 + tc * 4;
    float4 p4 = *(const float4*)(Pv + ncol);
    float4 m4 = *(const float4*)(Mv + ncol);
    float pa[4] = {p4.x, p4.y, p4.z, p4.w};
    float ma[4] = {m4.x, m4.y, m4.z, m4.w};
    #pragma unroll
    for (int i = 0; i < 8; ++i) {
        int m = m0 + tr * 8 + i;
        float ov[4];
        #pragma unroll
        for (int j = 0; j < 4; ++j) {
            float v = acc[i][j];
            ov[j] = fmaxf(v, 0.f) * pa[j] + fmaxf(-v, 0.f) * ma[j];
        }
        *(float4*)(Dst + (size_t)m * IN_ + ncol) = *(float4*)ov;
    }
}

// ---------------- sum over sequence ----------------
__global__ void k_sums(const float* __restrict__ X, float* __restrict__ Y) {
    int idx = blockIdx.x * 256 + threadIdx.x;      // [0, 32*8192)
    int b = idx >> 13, n = idx & 8191;
    const float* p = X + (size_t)b * 8 * IN_ + n;
    float s = 0.f;
    #pragma unroll
    for (int q = 0; q < 8; ++q) s += p[(size_t)q * IN_];
    Y[idx] = s;
}

// ---------------- MLP split-K partial GEMM ----------------
// partial[c][m][h] = sum_{k in chunk c} X[m,k] * W[k,h]
template<int M>
__global__ __launch_bounds__(256) void k_mlp_partial(
    const float* __restrict__ X, const float* __restrict__ W,
    float* __restrict__ P, int K, int H, int CK)
{
    __shared__ float Xs[M][64];
    int h  = blockIdx.x * 256 + threadIdx.x;
    int c  = blockIdx.y;
    int k0 = c * CK;
    float acc[M];
    #pragma unroll
    for (int m = 0; m < M; ++m) acc[m] = 0.f;

    for (int kt = 0; kt < CK; kt += 64) {
        for (int i = threadIdx.x; i < M * 64; i += 256) {
            int m = i >> 6, kk = i & 63;
            Xs[m][kk] = X[(size_t)m * K + k0 + kt + kk];
        }
        __syncthreads();
        #pragma unroll 4
        for (int kk = 0; kk < 64; ++kk) {
            float w = W[(size_t)(k0 + kt + kk) * H + h];
            #pragma unroll
            for (int m = 0; m < M; ++m) acc[m] = fmaf(Xs[m][kk], w, acc[m]);
        }
        __syncthreads();
    }
    #pragma unroll
    for (int m = 0; m < M; ++m) P[((size_t)c * M + m) * H + h] = acc[m];
}

// ---------------- reduce partials + bias (+relu) ----------------
__global__ void k_reduce(const float* __restrict__ P, const float* __restrict__ bias,
                         float* __restrict__ Y, int NC, int MH, int H, int do_relu) {
    int idx = blockIdx.x * 256 + threadIdx.x;
    if (idx >= MH) return;
    float s = bias[idx % H];
    for (int c = 0; c < NC; ++c) s += P[(size_t)c * MH + idx];
    Y[idx] = do_relu ? fmaxf(s, 0.f) : s;
}

extern "C" void kernel_launch(void* const* d_in, const int* in_sizes, int n_in,
                              void* d_out, int out_size, void* d_ws, size_t ws_size,
                              hipStream_t stream) {
    const float* xs0  = (const float*)d_in[0];
    const float* xs1  = (const float*)d_in[1];
    const float* xs2  = (const float*)d_in[2];
    const float* L0   = (const float*)d_in[3];
    const float* L1   = (const float*)d_in[4];
    const float* L2   = (const float*)d_in[5];
    const float* Wc0  = (const float*)d_in[6];
    const float* Wc1  = (const float*)d_in[7];
    const float* Wc2  = (const float*)d_in[8];
    const float* W_in = (const float*)d_in[9];
    const float* b_in = (const float*)d_in[10];
    const float* W_h  = (const float*)d_in[11];
    const float* b_h  = (const float*)d_in[12];
    const float* W_out= (const float*)d_in[13];
    const float* b_out= (const float*)d_in[14];

    float* ws   = (float*)d_ws;
    float* PM   = ws;                         // [2 layers][2 (P,M)][IN_]  = 32768
    float* xA   = PM + 4 * IN_;               // [BS_][IN_]
    float* xB   = xA + (size_t)BS_ * IN_;     // [BS_][IN_]
    float* hsum = xB + (size_t)BS_ * IN_;     // [32][IN_]
    float* p1   = hsum + 32 * IN_;            // [32][32][1024]
    float* h1   = p1 + 32 * 32 * 1024;        // [32][1024]
    float* p2   = h1 + 32 * 1024;             // [8][32][1024]
    float* h2   = p2 + 8 * 32 * 1024;         // [32][1024]
    float* p3   = h2 + 32 * 1024;             // [8][32][256]
    // total ~5.93M floats (~23 MB) of d_ws

    // P/M precompute
    k_prep<<<64, 256, 0, stream>>>(Wc0, Wc1, Wc2, PM);

    // conv layer 0: A = xs (per-branch lda = n_b), out -> xA (concat)
    k_conv<<<256, 256, 0, stream>>>(xs0, xs1, xs2, 2048, 4096, 2048,
                                    L0, L1, L2,
                                    PM + 0 * IN_, PM + 1 * IN_, xA);
    // conv layer 1: A = xA (concat, lda = IN_), out -> xB
    k_conv<<<256, 256, 0, stream>>>(xA, xA + 2048, xA + 6144, IN_, IN_, IN_,
                                    L0, L1, L2,
                                    PM + 2 * IN_, PM + 3 * IN_, xB);

    // sum over S
    k_sums<<<1024, 256, 0, stream>>>(xB, hsum);

    // MLP layer 1: [32,8192]@[8192,1024], split-K 32 chunks of 256
    {
        dim3 g(4, 32);
        k_mlp_partial<32><<<g, 256, 0, stream>>>(hsum, W_in, p1, IN_, H_, 256);
        k_reduce<<<128, 256, 0, stream>>>(p1, b_in, h1, 32, 32 * H_, H_, 1);
    }
    // MLP layer 2: [32,1024]@[1024,1024], split-K 8 chunks of 128
    {
        dim3 g(4, 8);
        k_mlp_partial<32><<<g, 256, 0, stream>>>(h1, W_h, p2, H_, H_, 128);
        k_reduce<<<128, 256, 0, stream>>>(p2, b_h, h2, 8, 32 * H_, H_, 1);
    }
    // MLP layer 3: [32,1024]@[1024,256], split-K 8 chunks of 128
    {
        dim3 g(1, 8);
        k_mlp_partial<32><<<g, 256, 0, stream>>>(h2, W_out, p3, H_, OUT_, 128);
        k_reduce<<<32, 256, 0, stream>>>(p3, b_out, (float*)d_out, 8, 32 * OUT_, OUT_, 0);
    }
}

// Round 2
// 581.752 us; speedup vs baseline: 1.4537x; 1.4537x over previous
//
#include <hip/hip_runtime.h>
#include <hip/hip_bf16.h>

// SCNN round 2: bf16 MFMA convs.
//  - x split hi/lo bf16 (2-term Markidis-lite), L single RNE bf16
//  - conv GEMM: no LDS, no barriers; per-lane 16B fragment loads straight from
//    global (both operands k-contiguous), L is L3-resident (50 MB bf16)
//  - mfma_f32_32x32x16_bf16, wave-tile 32x32, block 512 thr = 8 waves (2x4)
//  - grid 256 WGs -> 8 waves/CU
//  - MLP kept as round-1 f32 (measured ~54 us total non-conv)

#define B_    32
#define S_    8
#define BS_   256
#define F_    4
#define IN_   8192
#define H_    1024
#define OUT_  256

#define L_TOT  25165824LL     // 2048^2 + 4096^2 + 2048^2
#define LOFF1  4194304LL
#define LOFF2  20971520LL

typedef __attribute__((ext_vector_type(8)))  short bf16x8;
typedef __attribute__((ext_vector_type(4)))  short short4v;
typedef __attribute__((ext_vector_type(16))) float f32x16;

__device__ __forceinline__ unsigned short rne_bf16(float f) {
    unsigned int u = __builtin_bit_cast(unsigned int, f);
    u += 0x7FFFu + ((u >> 16) & 1u);
    return (unsigned short)(u >> 16);
}

// ---------------- P/M from Wc ----------------
__global__ void k_prep(const float* __restrict__ Wc0, const float* __restrict__ Wc1,
                       const float* __restrict__ Wc2, float* __restrict__ PM) {
    int idx = blockIdx.x * 256 + threadIdx.x;      // [0, 2*IN_)
    if (idx >= 2 * IN_) return;
    int l = idx / IN_, n = idx % IN_;
    const float* Wc; int nb, j;
    if (n < 2048)      { Wc = Wc0; nb = 2048; j = n;        }
    else if (n < 6144) { Wc = Wc1; nb = 4096; j = n - 2048; }
    else               { Wc = Wc2; nb = 2048; j = n - 6144; }
    float p = 0.f, m = 0.f;
    #pragma unroll
    for (int f = 0; f < F_; ++f) {
        float w = Wc[(l * F_ + f) * nb + j];
        p += fmaxf(w, 0.f);
        m += fmaxf(-w, 0.f);
    }
    PM[(l * 2 + 0) * IN_ + n] = p;
    PM[(l * 2 + 1) * IN_ + n] = m;
}

// ---------------- L f32 -> bf16 (concat) ----------------
__global__ void k_cvtL(const float* __restrict__ L0, const float* __restrict__ L1,
                       const float* __restrict__ L2, unsigned short* __restrict__ Lb) {
    long long e = ((long long)blockIdx.x * 256 + threadIdx.x) * 4;
    if (e >= L_TOT) return;
    const float* src; long long off;
    if (e < LOFF1)      { src = L0; off = 0; }
    else if (e < LOFF2) { src = L1; off = LOFF1; }
    else                { src = L2; off = LOFF2; }
    float4 v = *(const float4*)(src + (e - off));
    short4v o;
    o.x = (short)rne_bf16(v.x); o.y = (short)rne_bf16(v.y);
    o.z = (short)rne_bf16(v.z); o.w = (short)rne_bf16(v.w);
    *(short4v*)(Lb + e) = o;
}

// ---------------- xs -> concat hi/lo bf16 ----------------
__global__ void k_splitX(const float* __restrict__ x0, const float* __restrict__ x1,
                         const float* __restrict__ x2,
                         unsigned short* __restrict__ Xhi, unsigned short* __restrict__ Xlo) {
    int e = (blockIdx.x * 256 + threadIdx.x) * 4;   // over [256][8192]
    int m = e >> 13, c = e & 8191;
    const float* src; int n, c0;
    if (c < 2048)      { src = x0; n = 2048; c0 = c; }
    else if (c < 6144) { src = x1; n = 4096; c0 = c - 2048; }
    else               { src = x2; n = 2048; c0 = c - 6144; }
    float4 v = *(const float4*)(src + (size_t)m * n + c0);
    float a[4] = {v.x, v.y, v.z, v.w};
    short4v h, l;
    short hv[4], lv[4];
    #pragma unroll
    for (int i = 0; i < 4; ++i) {
        unsigned short hb = rne_bf16(a[i]);
        float hf = __builtin_bit_cast(float, (unsigned int)hb << 16);
        hv[i] = (short)hb;
        lv[i] = (short)rne_bf16(a[i] - hf);
    }
    h.x = hv[0]; h.y = hv[1]; h.z = hv[2]; h.w = hv[3];
    l.x = lv[0]; l.y = lv[1]; l.z = lv[2]; l.w = lv[3];
    *(short4v*)(Xhi + (size_t)m * IN_ + c) = h;
    *(short4v*)(Xlo + (size_t)m * IN_ + c) = l;
}

// ---------------- MFMA conv layer ----------------
// C[m,j] = sum_k X[m,k]*L[j,k]; X as hi+lo bf16 concat [256][8192], L bf16 concat.
// grid 256: b0 tiles [0,64): 4Mx16N; b1 [64,192): 4Mx32N; b2 [192,256): 4Mx16N.
// BM=64 (2 waves), BN=128 (4 waves); wave-tile 32x32 via one 32x32x16 mfma pair.
template<int LAYER>
__global__ __launch_bounds__(512) void k_conv_mfma(
    const unsigned short* __restrict__ Xhi, const unsigned short* __restrict__ Xlo,
    const unsigned short* __restrict__ Lb,
    const float* __restrict__ Pv, const float* __restrict__ Mv,
    unsigned short* __restrict__ Yhi, unsigned short* __restrict__ Ylo,  // LAYER==0 out
    float* __restrict__ Yf)                                               // LAYER==1 out
{
    int bx = blockIdx.x;
    int n_, noff, mt, nt; long long loff;
    if (bx < 64)       { int t = bx;       mt = t >> 4; nt = t & 15; n_ = 2048; noff = 0;    loff = 0;     }
    else if (bx < 192) { int t = bx - 64;  mt = t >> 5; nt = t & 31; n_ = 4096; noff = 2048; loff = LOFF1; }
    else               { int t = bx - 192; mt = t >> 4; nt = t & 15; n_ = 2048; noff = 6144; loff = LOFF2; }

    const int tid  = threadIdx.x;
    const int lane = tid & 63, wv = tid >> 6;
    const int wm = wv >> 2, wn = wv & 3;              // 2 x 4 wave grid
    const int l31 = lane & 31, kg = (lane >> 5) * 8;

    const int am = mt * 64 + wm * 32 + l31;           // output row (A-frag row)
    const int jj = nt * 128 + wn * 32 + l31;          // branch-local col (B-frag col)

    const unsigned short* pAh = Xhi + (size_t)am * IN_ + noff + kg;
    const unsigned short* pAl = Xlo + (size_t)am * IN_ + noff + kg;
    const unsigned short* pB  = Lb + loff + (size_t)jj * n_ + kg;

    f32x16 acc0 = {0.f}; f32x16 acc1 = {0.f};
    #pragma unroll
    for (int r = 0; r < 16; ++r) { acc0[r] = 0.f; acc1[r] = 0.f; }

    #pragma unroll 4
    for (int kt = 0; kt < n_; kt += 16) {
        bf16x8 ah = *(const bf16x8*)(pAh + kt);
        bf16x8 al = *(const bf16x8*)(pAl + kt);
        bf16x8 bb = *(const bf16x8*)(pB + kt);
        acc0 = __builtin_amdgcn_mfma_f32_32x32x16_bf16(ah, bb, acc0, 0, 0, 0);
        acc1 = __builtin_amdgcn_mfma_f32_32x32x16_bf16(al, bb, acc1, 0, 0, 0);
    }

    // epilogue: col = lane&31 (fixed per lane) -> scalar P/M
    const int colg = noff + jj;
    const float P = Pv[colg], M = Mv[colg];
    const int rbase = mt * 64 + wm * 32 + 4 * (lane >> 5);
    #pragma unroll
    for (int r = 0; r < 16; ++r) {
        int m = rbase + (r & 3) + 8 * (r >> 2);
        float v = acc0[r] + acc1[r];
        float y = fmaxf(v, 0.f) * P + fmaxf(-v, 0.f) * M;
        if (LAYER == 0) {
            unsigned short hb = rne_bf16(y);
            float hf = __builtin_bit_cast(float, (unsigned int)hb << 16);
            Yhi[(size_t)m * IN_ + colg] = hb;
            Ylo[(size_t)m * IN_ + colg] = rne_bf16(y - hf);
        } else {
            Yf[(size_t)m * IN_ + colg] = y;
        }
    }
}

// ---------------- sum over sequence ----------------
__global__ void k_sums(const float* __restrict__ X, float* __restrict__ Y) {
    int idx = blockIdx.x * 256 + threadIdx.x;      // [0, 32*8192)
    int b = idx >> 13, n = idx & 8191;
    const float* p = X + (size_t)b * 8 * IN_ + n;
    float s = 0.f;
    #pragma unroll
    for (int q = 0; q < 8; ++q) s += p[(size_t)q * IN_];
    Y[idx] = s;
}

// ---------------- MLP split-K partial GEMM ----------------
template<int M>
__global__ __launch_bounds__(256) void k_mlp_partial(
    const float* __restrict__ X, const float* __restrict__ W,
    float* __restrict__ P, int K, int H, int CK)
{
    __shared__ float Xs[M][64];
    int h  = blockIdx.x * 256 + threadIdx.x;
    int c  = blockIdx.y;
    int k0 = c * CK;
    float acc[M];
    #pragma unroll
    for (int m = 0; m < M; ++m) acc[m] = 0.f;

    for (int kt = 0; kt < CK; kt += 64) {
        for (int i = threadIdx.x; i < M * 64; i += 256) {
            int m = i >> 6, kk = i & 63;
            Xs[m][kk] = X[(size_t)m * K + k0 + kt + kk];
        }
        __syncthreads();
        #pragma unroll 4
        for (int kk = 0; kk < 64; ++kk) {
            float w = W[(size_t)(k0 + kt + kk) * H + h];
            #pragma unroll
            for (int m = 0; m < M; ++m) acc[m] = fmaf(Xs[m][kk], w, acc[m]);
        }
        __syncthreads();
    }
    #pragma unroll
    for (int m = 0; m < M; ++m) P[((size_t)c * M + m) * H + h] = acc[m];
}

// ---------------- reduce partials + bias (+relu) ----------------
__global__ void k_reduce(const float* __restrict__ P, const float* __restrict__ bias,
                         float* __restrict__ Y, int NC, int MH, int H, int do_relu) {
    int idx = blockIdx.x * 256 + threadIdx.x;
    if (idx >= MH) return;
    float s = bias[idx % H];
    for (int c = 0; c < NC; ++c) s += P[(size_t)c * MH + idx];
    Y[idx] = do_relu ? fmaxf(s, 0.f) : s;
}

extern "C" void kernel_launch(void* const* d_in, const int* in_sizes, int n_in,
                              void* d_out, int out_size, void* d_ws, size_t ws_size,
                              hipStream_t stream) {
    const float* xs0  = (const float*)d_in[0];
    const float* xs1  = (const float*)d_in[1];
    const float* xs2  = (const float*)d_in[2];
    const float* L0   = (const float*)d_in[3];
    const float* L1   = (const float*)d_in[4];
    const float* L2   = (const float*)d_in[5];
    const float* Wc0  = (const float*)d_in[6];
    const float* Wc1  = (const float*)d_in[7];
    const float* Wc2  = (const float*)d_in[8];
    const float* W_in = (const float*)d_in[9];
    const float* b_in = (const float*)d_in[10];
    const float* W_h  = (const float*)d_in[11];
    const float* b_h  = (const float*)d_in[12];
    const float* W_out= (const float*)d_in[13];
    const float* b_out= (const float*)d_in[14];

    char* w = (char*)d_ws;
    float*          PM  = (float*)w;          w += (size_t)4 * IN_ * 4;        // 128 KB
    unsigned short* Lb  = (unsigned short*)w; w += (size_t)L_TOT * 2;          // 50.3 MB
    unsigned short* Xhi = (unsigned short*)w; w += (size_t)BS_ * IN_ * 2;      // 4 MB
    unsigned short* Xlo = (unsigned short*)w; w += (size_t)BS_ * IN_ * 2;      // 4 MB
    unsigned short* Yhi = (unsigned short*)w; w += (size_t)BS_ * IN_ * 2;      // 4 MB
    unsigned short* Ylo = (unsigned short*)w; w += (size_t)BS_ * IN_ * 2;      // 4 MB
    float*          xB  = (float*)Xhi;        // alias: Xhi/Xlo dead after layer 0 (8 MB)
    float*          hsum= (float*)w;          w += (size_t)32 * IN_ * 4;       // 1 MB
    float*          p1  = (float*)w;          w += (size_t)32 * 32 * H_ * 4;   // 4 MB
    float*          h1  = (float*)w;          w += (size_t)32 * H_ * 4;
    float*          p2  = (float*)w;          w += (size_t)8 * 32 * H_ * 4;
    float*          h2  = (float*)w;          w += (size_t)32 * H_ * 4;
    float*          p3  = (float*)w;          w += (size_t)8 * 32 * OUT_ * 4;
    // total ~72 MB of d_ws

    k_prep<<<64, 256, 0, stream>>>(Wc0, Wc1, Wc2, PM);
    k_cvtL<<<24576, 256, 0, stream>>>(L0, L1, L2, Lb);
    k_splitX<<<2048, 256, 0, stream>>>(xs0, xs1, xs2, Xhi, Xlo);

    k_conv_mfma<0><<<256, 512, 0, stream>>>(Xhi, Xlo, Lb, PM + 0 * IN_, PM + 1 * IN_,
                                            Yhi, Ylo, nullptr);
    k_conv_mfma<1><<<256, 512, 0, stream>>>(Yhi, Ylo, Lb, PM + 2 * IN_, PM + 3 * IN_,
                                            nullptr, nullptr, xB);

    k_sums<<<1024, 256, 0, stream>>>(xB, hsum);

    {   // [32,8192]@[8192,1024], split-K 32 x 256
        dim3 g(4, 32);
        k_mlp_partial<32><<<g, 256, 0, stream>>>(hsum, W_in, p1, IN_, H_, 256);
        k_reduce<<<128, 256, 0, stream>>>(p1, b_in, h1, 32, 32 * H_, H_, 1);
    }
    {   // [32,1024]@[1024,1024], split-K 8 x 128
        dim3 g(4, 8);
        k_mlp_partial<32><<<g, 256, 0, stream>>>(h1, W_h, p2, H_, H_, 128);
        k_reduce<<<128, 256, 0, stream>>>(p2, b_h, h2, 8, 32 * H_, H_, 1);
    }
    {   // [32,1024]@[1024,256], split-K 8 x 128
        dim3 g(1, 8);
        k_mlp_partial<32><<<g, 256, 0, stream>>>(h2, W_out, p3, H_, OUT_, 128);
        k_reduce<<<32, 256, 0, stream>>>(p3, b_out, (float*)d_out, 8, 32 * OUT_, OUT_, 0);
    }
}

// Round 3
// 270.548 us; speedup vs baseline: 3.1258x; 2.1503x over previous
//
#include <hip/hip_runtime.h>
#include <hip/hip_bf16.h>

// SCNN round 3: LDS-staged double-buffered MFMA conv GEMM.
//  - hi/lo bf16 split stacked as M=512 rows; split-K=2 -> 512 blocks (2/CU)
//  - BM=128 BN=128 BK=64, 4 waves, wave 64x64 (4x mfma_f32_32x32x16_bf16 accs)
//  - global_load_lds width 16, XOR-swizzle (row&7)<<4 via pre-swizzled source
//  - epilogue kernels: partial+hi/lo add, relu*P/M, re-split for next layer

#define B_    32
#define S_    8
#define BS_   256
#define F_    4
#define IN_   8192
#define H_    1024
#define OUT_  256

#define L_TOT  25165824LL     // 2048^2 + 4096^2 + 2048^2
#define LOFF1  4194304LL
#define LOFF2  20971520LL

typedef __attribute__((ext_vector_type(8)))  short bf16x8;
typedef __attribute__((ext_vector_type(4)))  short short4v;
typedef __attribute__((ext_vector_type(16))) float f32x16;

typedef const __attribute__((address_space(1))) void* gas_ptr;
typedef __attribute__((address_space(3))) void* las_ptr;

__device__ __forceinline__ void gload16(const void* g, void* s) {
    __builtin_amdgcn_global_load_lds((gas_ptr)g, (las_ptr)s, 16, 0, 0);
}

__device__ __forceinline__ unsigned short rne_bf16(float f) {
    unsigned int u = __builtin_bit_cast(unsigned int, f);
    u += 0x7FFFu + ((u >> 16) & 1u);
    return (unsigned short)(u >> 16);
}

// ---------------- P/M from Wc ----------------
__global__ void k_prep(const float* __restrict__ Wc0, const float* __restrict__ Wc1,
                       const float* __restrict__ Wc2, float* __restrict__ PM) {
    int idx = blockIdx.x * 256 + threadIdx.x;
    if (idx >= 2 * IN_) return;
    int l = idx / IN_, n = idx % IN_;
    const float* Wc; int nb, j;
    if (n < 2048)      { Wc = Wc0; nb = 2048; j = n;        }
    else if (n < 6144) { Wc = Wc1; nb = 4096; j = n - 2048; }
    else               { Wc = Wc2; nb = 2048; j = n - 6144; }
    float p = 0.f, m = 0.f;
    #pragma unroll
    for (int f = 0; f < F_; ++f) {
        float w = Wc[(l * F_ + f) * nb + j];
        p += fmaxf(w, 0.f);
        m += fmaxf(-w, 0.f);
    }
    PM[(l * 2 + 0) * IN_ + n] = p;
    PM[(l * 2 + 1) * IN_ + n] = m;
}

// ---------------- L f32 -> bf16 (concat) ----------------
__global__ void k_cvtL(const float* __restrict__ L0, const float* __restrict__ L1,
                       const float* __restrict__ L2, unsigned short* __restrict__ Lb) {
    long long e = ((long long)blockIdx.x * 256 + threadIdx.x) * 4;
    if (e >= L_TOT) return;
    const float* src; long long off;
    if (e < LOFF1)      { src = L0; off = 0; }
    else if (e < LOFF2) { src = L1; off = LOFF1; }
    else                { src = L2; off = LOFF2; }
    float4 v = *(const float4*)(src + (e - off));
    short4v o;
    o.x = (short)rne_bf16(v.x); o.y = (short)rne_bf16(v.y);
    o.z = (short)rne_bf16(v.z); o.w = (short)rne_bf16(v.w);
    *(short4v*)(Lb + e) = o;
}

// ---------------- xs -> stacked hi/lo bf16 [512][8192] ----------------
__global__ void k_splitX(const float* __restrict__ x0, const float* __restrict__ x1,
                         const float* __restrict__ x2,
                         unsigned short* __restrict__ Xhi, unsigned short* __restrict__ Xlo) {
    int e = (blockIdx.x * 256 + threadIdx.x) * 4;
    int m = e >> 13, c = e & 8191;
    const float* src; int n, c0;
    if (c < 2048)      { src = x0; n = 2048; c0 = c; }
    else if (c < 6144) { src = x1; n = 4096; c0 = c - 2048; }
    else               { src = x2; n = 2048; c0 = c - 6144; }
    float4 v = *(const float4*)(src + (size_t)m * n + c0);
    float a[4] = {v.x, v.y, v.z, v.w};
    short hv[4], lv[4];
    #pragma unroll
    for (int i = 0; i < 4; ++i) {
        unsigned short hb = rne_bf16(a[i]);
        float hf = __builtin_bit_cast(float, (unsigned int)hb << 16);
        hv[i] = (short)hb;
        lv[i] = (short)rne_bf16(a[i] - hf);
    }
    short4v h = {hv[0], hv[1], hv[2], hv[3]};
    short4v l = {lv[0], lv[1], lv[2], lv[3]};
    *(short4v*)(Xhi + (size_t)m * IN_ + c) = h;
    *(short4v*)(Xlo + (size_t)m * IN_ + c) = l;
}

// ---------------- MFMA GEMM: pf[sk][512][8192] partial = Astk . Lb^T ----------------
// grid 512: sk = bx&1, tile = bx>>1; tiles: b0 [0,64), b1 [64,192), b2 [192,256)
__global__ __launch_bounds__(256, 2) void k_gemm(
    const unsigned short* __restrict__ Astk,   // [512][8192] stacked hi/lo
    const unsigned short* __restrict__ Lb,     // concat bf16 L
    float* __restrict__ pf)                    // [2][512][8192]
{
    __shared__ __attribute__((aligned(16))) unsigned short ldsA[2][128 * 64];
    __shared__ __attribute__((aligned(16))) unsigned short ldsB[2][128 * 64];

    const int bx = blockIdx.x;
    const int sk = bx & 1, t = bx >> 1;
    int n_, noff, mt, nt; long long loff;
    if (t < 64)       { mt = t >> 4;         nt = t & 15;        n_ = 2048; noff = 0;    loff = 0;     }
    else if (t < 192) { int u = t - 64;  mt = u >> 5; nt = u & 31; n_ = 4096; noff = 2048; loff = LOFF1; }
    else              { int u = t - 192; mt = u >> 4; nt = u & 15; n_ = 2048; noff = 6144; loff = LOFF2; }

    const int tid = threadIdx.x, l = tid & 63, w = tid >> 6;
    const int n2 = n_ >> 1, k0 = sk * n2, iters = n2 >> 6;

    // ----- staging source pointers (pre-swizzled columns, rule #21) -----
    // inst q covers 8 rows (w*32 + q*8 + l>>3); lane byte-in-row (l&7)*16 ^ ((row&7)<<4)
    const int srow = w * 32 + (l >> 3);
    const int cswz = ((l & 7) ^ (l >> 3)) << 3;   // ushort offset
    const unsigned short* gA = Astk + (size_t)(mt * 128 + srow) * IN_ + noff + k0 + cswz;
    const unsigned short* gB = Lb + loff + (size_t)(nt * 128 + srow) * n_ + k0 + cswz;

    // ----- compute-side fragment addressing -----
    const int l31 = l & 31, lh = l >> 5, l7 = l31 & 7;
    const int wm = w >> 1, wn = w & 1;
    const int arow = (wm * 64 + l31) * 64;        // ushort idx of row base
    const int brow = (wn * 64 + l31) * 64;

    f32x16 a00, a01, a10, a11;
    #pragma unroll
    for (int r = 0; r < 16; ++r) { a00[r] = 0.f; a01[r] = 0.f; a10[r] = 0.f; a11[r] = 0.f; }

    // prologue: stage buffer 0
    #pragma unroll
    for (int q = 0; q < 4; ++q) {
        gload16(gA + (size_t)q * 8 * IN_, &ldsA[0][(w * 32 + q * 8) * 64]);
        gload16(gB + (size_t)q * 8 * n_, &ldsB[0][(w * 32 + q * 8) * 64]);
    }
    __syncthreads();

    for (int it = 0; it < iters; ++it) {
        const unsigned short* La = (it & 1) ? &ldsA[1][0] : &ldsA[0][0];
        const unsigned short* Bb = (it & 1) ? &ldsB[1][0] : &ldsB[0][0];
        unsigned short* Sa = (it & 1) ? &ldsA[0][0] : &ldsA[1][0];
        unsigned short* Sb = (it & 1) ? &ldsB[0][0] : &ldsB[1][0];

        if (it + 1 < iters) {
            const int kofs = (it + 1) * 64;
            #pragma unroll
            for (int q = 0; q < 4; ++q) {
                gload16(gA + (size_t)q * 8 * IN_ + kofs, Sa + (w * 32 + q * 8) * 64);
                gload16(gB + (size_t)q * 8 * n_ + kofs, Sb + (w * 32 + q * 8) * 64);
            }
        }

        #pragma unroll
        for (int t2 = 0; t2 < 4; ++t2) {
            const int xs = (((t2 * 2 + lh) ^ l7) << 3);
            bf16x8 fa0 = *(const bf16x8*)&La[arow + xs];
            bf16x8 fa1 = *(const bf16x8*)&La[arow + 32 * 64 + xs];
            bf16x8 fb0 = *(const bf16x8*)&Bb[brow + xs];
            bf16x8 fb1 = *(const bf16x8*)&Bb[brow + 32 * 64 + xs];
            a00 = __builtin_amdgcn_mfma_f32_32x32x16_bf16(fa0, fb0, a00, 0, 0, 0);
            a01 = __builtin_amdgcn_mfma_f32_32x32x16_bf16(fa0, fb1, a01, 0, 0, 0);
            a10 = __builtin_amdgcn_mfma_f32_32x32x16_bf16(fa1, fb0, a10, 0, 0, 0);
            a11 = __builtin_amdgcn_mfma_f32_32x32x16_bf16(fa1, fb1, a11, 0, 0, 0);
        }
        __syncthreads();
    }

    // ----- partial store (f32) -----
    const int gcolb = noff + nt * 128 + wn * 64 + l31;
    float* po = pf + ((size_t)sk * 512 + (size_t)mt * 128 + wm * 64 + 4 * lh) * IN_;
    #pragma unroll
    for (int r = 0; r < 16; ++r) {
        int row = (r & 3) + 8 * (r >> 2);
        po[(size_t)row * IN_ + gcolb]           = a00[r];
        po[(size_t)row * IN_ + gcolb + 32]      = a01[r];
        po[(size_t)(row + 32) * IN_ + gcolb]    = a10[r];
        po[(size_t)(row + 32) * IN_ + gcolb+32] = a11[r];
    }
}

// ---------------- epilogue: partial+hi/lo add, relu*P/M, re-split ----------------
template<int LAYER>
__global__ void k_epi(const float* __restrict__ pf,
                      const float* __restrict__ Pv, const float* __restrict__ Mv,
                      unsigned short* __restrict__ Yhi, unsigned short* __restrict__ Ylo,
                      float* __restrict__ Yf) {
    int e = (blockIdx.x * 256 + threadIdx.x) * 4;   // over [256][8192]
    int m = e >> 13, c = e & 8191;
    const float* p0 = pf + (size_t)m * IN_ + c;
    float4 vh0 = *(const float4*)(p0);
    float4 vl0 = *(const float4*)(p0 + (size_t)256 * IN_);
    float4 vh1 = *(const float4*)(p0 + (size_t)512 * IN_);
    float4 vl1 = *(const float4*)(p0 + (size_t)768 * IN_);
    float4 pv = *(const float4*)(Pv + c);
    float4 mv = *(const float4*)(Mv + c);
    float vs[4] = {vh0.x + vl0.x + vh1.x + vl1.x, vh0.y + vl0.y + vh1.y + vl1.y,
                   vh0.z + vl0.z + vh1.z + vl1.z, vh0.w + vl0.w + vh1.w + vl1.w};
    float pa[4] = {pv.x, pv.y, pv.z, pv.w};
    float ma[4] = {mv.x, mv.y, mv.z, mv.w};
    if (LAYER == 0) {
        short hv[4], lv[4];
        #pragma unroll
        for (int j = 0; j < 4; ++j) {
            float y = fmaxf(vs[j], 0.f) * pa[j] + fmaxf(-vs[j], 0.f) * ma[j];
            unsigned short hb = rne_bf16(y);
            float hf = __builtin_bit_cast(float, (unsigned int)hb << 16);
            hv[j] = (short)hb;
            lv[j] = (short)rne_bf16(y - hf);
        }
        short4v h = {hv[0], hv[1], hv[2], hv[3]};
        short4v lo = {lv[0], lv[1], lv[2], lv[3]};
        *(short4v*)(Yhi + (size_t)m * IN_ + c) = h;
        *(short4v*)(Ylo + (size_t)m * IN_ + c) = lo;
    } else {
        float ov[4];
        #pragma unroll
        for (int j = 0; j < 4; ++j)
            ov[j] = fmaxf(vs[j], 0.f) * pa[j] + fmaxf(-vs[j], 0.f) * ma[j];
        *(float4*)(Yf + (size_t)m * IN_ + c) = *(float4*)ov;
    }
}

// ---------------- sum over sequence ----------------
__global__ void k_sums(const float* __restrict__ X, float* __restrict__ Y) {
    int idx = blockIdx.x * 256 + threadIdx.x;
    int b = idx >> 13, n = idx & 8191;
    const float* p = X + (size_t)b * 8 * IN_ + n;
    float s = 0.f;
    #pragma unroll
    for (int q = 0; q < 8; ++q) s += p[(size_t)q * IN_];
    Y[idx] = s;
}

// ---------------- MLP split-K partial GEMM ----------------
template<int M>
__global__ __launch_bounds__(256) void k_mlp_partial(
    const float* __restrict__ X, const float* __restrict__ W,
    float* __restrict__ P, int K, int H, int CK)
{
    __shared__ float Xs[M][64];
    int h  = blockIdx.x * 256 + threadIdx.x;
    int c  = blockIdx.y;
    int k0 = c * CK;
    float acc[M];
    #pragma unroll
    for (int m = 0; m < M; ++m) acc[m] = 0.f;

    for (int kt = 0; kt < CK; kt += 64) {
        for (int i = threadIdx.x; i < M * 64; i += 256) {
            int m = i >> 6, kk = i & 63;
            Xs[m][kk] = X[(size_t)m * K + k0 + kt + kk];
        }
        __syncthreads();
        #pragma unroll 4
        for (int kk = 0; kk < 64; ++kk) {
            float w = W[(size_t)(k0 + kt + kk) * H + h];
            #pragma unroll
            for (int m = 0; m < M; ++m) acc[m] = fmaf(Xs[m][kk], w, acc[m]);
        }
        __syncthreads();
    }
    #pragma unroll
    for (int m = 0; m < M; ++m) P[((size_t)c * M + m) * H + h] = acc[m];
}

// ---------------- reduce partials + bias (+relu) ----------------
__global__ void k_reduce(const float* __restrict__ P, const float* __restrict__ bias,
                         float* __restrict__ Y, int NC, int MH, int H, int do_relu) {
    int idx = blockIdx.x * 256 + threadIdx.x;
    if (idx >= MH) return;
    float s = bias[idx % H];
    for (int c = 0; c < NC; ++c) s += P[(size_t)c * MH + idx];
    Y[idx] = do_relu ? fmaxf(s, 0.f) : s;
}

extern "C" void kernel_launch(void* const* d_in, const int* in_sizes, int n_in,
                              void* d_out, int out_size, void* d_ws, size_t ws_size,
                              hipStream_t stream) {
    const float* xs0  = (const float*)d_in[0];
    const float* xs1  = (const float*)d_in[1];
    const float* xs2  = (const float*)d_in[2];
    const float* L0   = (const float*)d_in[3];
    const float* L1   = (const float*)d_in[4];
    const float* L2   = (const float*)d_in[5];
    const float* Wc0  = (const float*)d_in[6];
    const float* Wc1  = (const float*)d_in[7];
    const float* Wc2  = (const float*)d_in[8];
    const float* W_in = (const float*)d_in[9];
    const float* b_in = (const float*)d_in[10];
    const float* W_h  = (const float*)d_in[11];
    const float* b_h  = (const float*)d_in[12];
    const float* W_out= (const float*)d_in[13];
    const float* b_out= (const float*)d_in[14];

    char* w = (char*)d_ws;
    float*          PM = (float*)w;           w += (size_t)4 * IN_ * 4;            // 128 KB
    unsigned short* Lb = (unsigned short*)w;  w += (size_t)L_TOT * 2;              // 50.3 MB
    unsigned short* Xs = (unsigned short*)w;  w += (size_t)512 * IN_ * 2;          // 8 MB
    unsigned short* Ys = (unsigned short*)w;  w += (size_t)512 * IN_ * 2;          // 8 MB
    float*          pf = (float*)w;           w += (size_t)2 * 512 * IN_ * 4;      // 32 MB
    float*          xB = (float*)Xs;          // alias: Xs dead after layer-0 GEMM
    float*          hsum = (float*)w;         w += (size_t)32 * IN_ * 4;           // 1 MB
    float*          p1 = (float*)w;           w += (size_t)64 * 32 * H_ * 4;       // 8 MB
    float*          h1 = (float*)w;           w += (size_t)32 * H_ * 4;
    float*          p2 = (float*)w;           w += (size_t)8 * 32 * H_ * 4;
    float*          h2 = (float*)w;           w += (size_t)32 * H_ * 4;
    float*          p3 = (float*)w;           w += (size_t)8 * 32 * OUT_ * 4;

    k_prep<<<64, 256, 0, stream>>>(Wc0, Wc1, Wc2, PM);
    k_cvtL<<<24576, 256, 0, stream>>>(L0, L1, L2, Lb);
    k_splitX<<<2048, 256, 0, stream>>>(xs0, xs1, xs2, Xs, Xs + (size_t)256 * IN_);

    k_gemm<<<512, 256, 0, stream>>>(Xs, Lb, pf);
    k_epi<0><<<2048, 256, 0, stream>>>(pf, PM + 0 * IN_, PM + 1 * IN_,
                                       Ys, Ys + (size_t)256 * IN_, nullptr);
    k_gemm<<<512, 256, 0, stream>>>(Ys, Lb, pf);
    k_epi<1><<<2048, 256, 0, stream>>>(pf, PM + 2 * IN_, PM + 3 * IN_,
                                       nullptr, nullptr, xB);

    k_sums<<<1024, 256, 0, stream>>>(xB, hsum);

    {   // [32,8192]@[8192,1024], split-K 64 x 128
        dim3 g(4, 64);
        k_mlp_partial<32><<<g, 256, 0, stream>>>(hsum, W_in, p1, IN_, H_, 128);
        k_reduce<<<128, 256, 0, stream>>>(p1, b_in, h1, 64, 32 * H_, H_, 1);
    }
    {   // [32,1024]@[1024,1024], split-K 8 x 128
        dim3 g(4, 8);
        k_mlp_partial<32><<<g, 256, 0, stream>>>(h1, W_h, p2, H_, H_, 128);
        k_reduce<<<128, 256, 0, stream>>>(p2, b_h, h2, 8, 32 * H_, H_, 1);
    }
    {   // [32,1024]@[1024,256], split-K 8 x 128
        dim3 g(1, 8);
        k_mlp_partial<32><<<g, 256, 0, stream>>>(h2, W_out, p3, H_, OUT_, 128);
        k_reduce<<<32, 256, 0, stream>>>(p3, b_out, (float*)d_out, 8, 32 * OUT_, OUT_, 0);
    }
}